// Round 1
// baseline (1262.231 us; speedup 1.0000x reference)
//
#include <hip/hip_runtime.h>

// Problem constants
constexpr int N_TOK = 8192;      // B*S
constexpr int D_IN  = 2048;
constexpr int H_OUT = 4096;
constexpr int NEXP  = 8;
constexpr int TOPK  = 2;
constexpr float ENT_W = 0.1f;
constexpr float MAX_USAGE = 0.3f;

// GEMM tiling
constexpr int TM = 128;               // token-tile
constexpr int TH = 128;               // H-tile
constexpr int BK = 32;                // K-step
constexpr int TILES_H = H_OUT / TH;   // 32
constexpr int TM_MAX  = N_TOK / TM;   // 64 worst-case token tiles per expert

typedef __attribute__((ext_vector_type(8))) short bf16x8;
typedef __attribute__((ext_vector_type(4))) float f32x4;

__device__ __forceinline__ short f2bf(float f) {
    unsigned u = __float_as_uint(f);
    u += 0x7FFF + ((u >> 16) & 1);   // RNE
    return (short)(u >> 16);
}

// ---------------------------------------------------------------------------
// Kernel 1: gating. One wave per token. Computes logits, softmax, entropy,
// top-2, writes per-token (idx, prob); int-atomic counts; per-block entropy
// partial sums (deterministic).
// ---------------------------------------------------------------------------
__global__ __launch_bounds__(256) void gate_kernel(
    const float* __restrict__ x, const float* __restrict__ gate_w,
    const float* __restrict__ gate_b, int* __restrict__ topk_idx,
    float* __restrict__ topk_w, int* __restrict__ counts,
    float* __restrict__ ent_partial)
{
    __shared__ float ent_s[4];
    const int wv = threadIdx.x >> 6;
    const int lane = threadIdx.x & 63;
    const int t = blockIdx.x * 4 + wv;

    float acc[NEXP];
#pragma unroll
    for (int e = 0; e < NEXP; ++e) acc[e] = 0.f;

    const float4* xr = (const float4*)(x + (size_t)t * D_IN);
#pragma unroll
    for (int i = 0; i < D_IN / 256; ++i) {           // 8 iters
        float4 xv = xr[lane + i * 64];
#pragma unroll
        for (int e = 0; e < NEXP; ++e) {
            float4 gv = ((const float4*)(gate_w + e * D_IN))[lane + i * 64];
            acc[e] += xv.x * gv.x + xv.y * gv.y + xv.z * gv.z + xv.w * gv.w;
        }
    }
#pragma unroll
    for (int e = 0; e < NEXP; ++e)
#pragma unroll
        for (int m = 32; m >= 1; m >>= 1) acc[e] += __shfl_xor(acc[e], m, 64);

    if (lane == 0) {
        float lg[NEXP], p[NEXP];
        float mx = -1e30f;
#pragma unroll
        for (int e = 0; e < NEXP; ++e) { lg[e] = acc[e] + gate_b[e]; mx = fmaxf(mx, lg[e]); }
        float s = 0.f;
#pragma unroll
        for (int e = 0; e < NEXP; ++e) { p[e] = __expf(lg[e] - mx); s += p[e]; }
        // use precise expf to stay close to numpy
        s = 0.f;
#pragma unroll
        for (int e = 0; e < NEXP; ++e) { p[e] = expf(lg[e] - mx); s += p[e]; }
        float inv = 1.f / s;
        float ent = 0.f;
#pragma unroll
        for (int e = 0; e < NEXP; ++e) { p[e] *= inv; ent -= p[e] * logf(p[e] + 1e-10f); }
        // top-1 (first occurrence on ties, matches lax.top_k)
        int e1 = 0; float b1 = p[0];
#pragma unroll
        for (int e = 1; e < NEXP; ++e) if (p[e] > b1) { b1 = p[e]; e1 = e; }
        int e2 = (e1 == 0) ? 1 : 0; float b2 = p[e2];
#pragma unroll
        for (int e = 0; e < NEXP; ++e)
            if (e != e1 && e != ((e1 == 0) ? 1 : 0) && p[e] > b2) { b2 = p[e]; e2 = e; }
        topk_idx[2 * t]     = e1;  topk_idx[2 * t + 1] = e2;
        topk_w[2 * t]       = b1;  topk_w[2 * t + 1]   = b2;
        atomicAdd(&counts[e1], 1);
        atomicAdd(&counts[e2], 1);
        ent_s[wv] = ent;
    }
    __syncthreads();
    if (threadIdx.x == 0)
        ent_partial[blockIdx.x] = ent_s[0] + ent_s[1] + ent_s[2] + ent_s[3];
}

// ---------------------------------------------------------------------------
// Kernel 2: finalize — reduce entropy partials, compute loss scalar, offsets.
// ---------------------------------------------------------------------------
__global__ __launch_bounds__(256) void finalize_kernel(
    const int* __restrict__ counts, const float* __restrict__ ent_partial,
    int* __restrict__ offsets, float* __restrict__ loss_out)
{
    __shared__ float red[256];
    float s = 0.f;
    for (int i = threadIdx.x; i < N_TOK / 4; i += 256) s += ent_partial[i];
    red[threadIdx.x] = s;
    __syncthreads();
    for (int st = 128; st > 0; st >>= 1) {
        if (threadIdx.x < st) red[threadIdx.x] += red[threadIdx.x + st];
        __syncthreads();
    }
    if (threadIdx.x == 0) {
        float loss = ENT_W * red[0] / (float)N_TOK;
        int off = 0;
        for (int e = 0; e < NEXP; ++e) {
            offsets[e] = off; off += counts[e];
            float r = (float)counts[e] / (float)N_TOK - MAX_USAGE;
            if (r > 0.f) loss += r;
        }
        loss_out[0] = loss;
    }
}

// ---------------------------------------------------------------------------
// Kernel 3: scatter (token, weight) pairs into per-expert lists.
// Positions are race-dependent, but final output is invariant to row order.
// ---------------------------------------------------------------------------
__global__ __launch_bounds__(256) void scatter_kernel(
    const int* __restrict__ topk_idx, const float* __restrict__ topk_w,
    const int* __restrict__ offsets, int* __restrict__ cursors,
    int* __restrict__ tok_list, float* __restrict__ w_list)
{
    int t = blockIdx.x * 256 + threadIdx.x;
#pragma unroll
    for (int k = 0; k < TOPK; ++k) {
        int e = topk_idx[2 * t + k];
        float w = topk_w[2 * t + k];
        int pos = atomicAdd(&cursors[e], 1);
        int dst = offsets[e] + pos;
        tok_list[dst] = t;
        w_list[dst] = w;
    }
}

// ---------------------------------------------------------------------------
// Kernel 4: grouped GEMM. Grid = E * TM_MAX * TILES_H; inactive tiles exit.
// 128x128 tile, BK=32, 4 waves of 4x4 16x16x32 bf16 MFMA. fp32 global ->
// bf16 LDS (reg-staged convert). LDS layout [kgroup][row][8] (2-way, free).
// Epilogue: atomicAdd of weight*(acc+bias) into fp32 out.
// ---------------------------------------------------------------------------
__global__ __launch_bounds__(256) void moe_gemm(
    const float* __restrict__ x, const float* __restrict__ expert_w,
    const float* __restrict__ expert_b, const int* __restrict__ tok_list,
    const float* __restrict__ w_list, const int* __restrict__ counts,
    const int* __restrict__ offsets, float* __restrict__ out)
{
    const int bid = blockIdx.x;
    const int e  = bid / (TM_MAX * TILES_H);
    const int rem = bid % (TM_MAX * TILES_H);
    const int tm = rem / TILES_H;
    const int th = rem % TILES_H;

    const int cnt = counts[e];
    if (tm * TM >= cnt) return;
    const int base = offsets[e] + tm * TM;

    __shared__ int   tok_s[TM];
    __shared__ float wgt_s[TM];
    __shared__ __align__(16) short A_s[4 * 128 * 8];   // 8 KB
    __shared__ __align__(16) short B_s[4 * 128 * 8];   // 8 KB

    const int tid = threadIdx.x;
    if (tid < TM) {
        int li = tm * TM + tid;
        bool v = li < cnt;
        tok_s[tid] = v ? tok_list[base + tid] : 0;
        wgt_s[tid] = v ? w_list[base + tid] : 0.f;
    }
    __syncthreads();

    // staging assignment: 1024 float4-chunks per tile; 4 per thread
    const float* aptr[4];
    const float* bptr[4];
    int soff[4];
#pragma unroll
    for (int i = 0; i < 4; ++i) {
        int f = tid + i * 256;
        int row = f >> 3, c4 = f & 7;
        aptr[i] = x + (size_t)tok_s[row] * D_IN + c4 * 4;
        bptr[i] = expert_w + ((size_t)e * H_OUT + th * TH + row) * (size_t)D_IN + c4 * 4;
        soff[i] = (c4 >> 1) * 1024 + row * 8 + (c4 & 1) * 4;
    }

    const int lane = tid & 63;
    const int wv = tid >> 6;
    const int wr = wv >> 1, wc = wv & 1;
    const int rr = lane & 15, kg = lane >> 4;
    const int aoff = kg * 1024 + (wr * 64 + rr) * 8;
    const int boff = kg * 1024 + (wc * 64 + rr) * 8;

    f32x4 acc[4][4] = {};

    for (int kk = 0; kk < D_IN / BK; ++kk) {
#pragma unroll
        for (int i = 0; i < 4; ++i) {
            float4 va = *(const float4*)aptr[i]; aptr[i] += BK;
            float4 vb = *(const float4*)bptr[i]; bptr[i] += BK;
            short4 sa, sb;
            sa.x = f2bf(va.x); sa.y = f2bf(va.y); sa.z = f2bf(va.z); sa.w = f2bf(va.w);
            sb.x = f2bf(vb.x); sb.y = f2bf(vb.y); sb.z = f2bf(vb.z); sb.w = f2bf(vb.w);
            *(short4*)&A_s[soff[i]] = sa;
            *(short4*)&B_s[soff[i]] = sb;
        }
        __syncthreads();

        bf16x8 af[4], bv[4];
#pragma unroll
        for (int mi = 0; mi < 4; ++mi) af[mi] = *(const bf16x8*)&A_s[aoff + mi * 128];
#pragma unroll
        for (int ni = 0; ni < 4; ++ni) bv[ni] = *(const bf16x8*)&B_s[boff + ni * 128];
#pragma unroll
        for (int mi = 0; mi < 4; ++mi)
#pragma unroll
            for (int ni = 0; ni < 4; ++ni)
                acc[mi][ni] = __builtin_amdgcn_mfma_f32_16x16x32_bf16(
                    af[mi], bv[ni], acc[mi][ni], 0, 0, 0);
        __syncthreads();
    }

    // epilogue
    const float* bias = expert_b + (size_t)e * H_OUT + th * TH;
#pragma unroll
    for (int mi = 0; mi < 4; ++mi) {
#pragma unroll
        for (int ni = 0; ni < 4; ++ni) {
            int col = wc * 64 + ni * 16 + (lane & 15);
            float be = bias[col];
#pragma unroll
            for (int i = 0; i < 4; ++i) {
                int r = wr * 64 + mi * 16 + (lane >> 4) * 4 + i;
                float val = wgt_s[r] * (acc[mi][ni][i] + be);
                atomicAdd(&out[(size_t)tok_s[r] * H_OUT + th * TH + col], val);
            }
        }
    }
}

// ---------------------------------------------------------------------------
extern "C" void kernel_launch(void* const* d_in, const int* in_sizes, int n_in,
                              void* d_out, int out_size, void* d_ws, size_t ws_size,
                              hipStream_t stream) {
    const float* x        = (const float*)d_in[0];
    const float* gate_w   = (const float*)d_in[1];
    const float* gate_b   = (const float*)d_in[2];
    const float* expert_w = (const float*)d_in[3];
    const float* expert_b = (const float*)d_in[4];
    float* out = (float*)d_out;
    char* ws = (char*)d_ws;

    int*   topk_idx    = (int*)(ws);                        // 64 KB
    float* topk_w      = (float*)(ws + (64 << 10));         // 64 KB
    int*   counts      = (int*)(ws + (128 << 10));          // 32 B
    int*   cursors     = (int*)(ws + (128 << 10) + 64);     // 32 B
    int*   offsets     = (int*)(ws + (128 << 10) + 128);    // 32 B
    float* ent_partial = (float*)(ws + (128 << 10) + 256);  // 8 KB
    int*   tok_list    = (int*)(ws + (160 << 10));          // 64 KB
    float* w_list      = (float*)(ws + (224 << 10));        // 64 KB

    hipMemsetAsync(counts, 0, 256, stream);                 // counts+cursors
    hipMemsetAsync(d_out, 0, (size_t)out_size * sizeof(float), stream);

    gate_kernel<<<N_TOK / 4, 256, 0, stream>>>(x, gate_w, gate_b, topk_idx,
                                               topk_w, counts, ent_partial);
    finalize_kernel<<<1, 256, 0, stream>>>(counts, ent_partial, offsets,
                                           out + (size_t)N_TOK * H_OUT);
    scatter_kernel<<<N_TOK / 256, 256, 0, stream>>>(topk_idx, topk_w, offsets,
                                                    cursors, tok_list, w_list);
    moe_gemm<<<NEXP * TM_MAX * TILES_H, 256, 0, stream>>>(
        x, expert_w, expert_b, tok_list, w_list, counts, offsets, out);
}

// Round 2
// 1023.526 us; speedup vs baseline: 1.2332x; 1.2332x over previous
//
#include <hip/hip_runtime.h>

// Problem constants
constexpr int N_TOK = 8192;      // B*S
constexpr int D_IN  = 2048;
constexpr int H_OUT = 4096;
constexpr int NEXP  = 8;
constexpr int TOPK  = 2;
constexpr float ENT_W = 0.1f;
constexpr float MAX_USAGE = 0.3f;

// GEMM tiling
constexpr int TM = 128;               // token-tile
constexpr int TH = 128;               // H-tile
constexpr int BK = 64;                // K-step (128 bytes bf16 per row)
constexpr int TILES_H = H_OUT / TH;   // 32
constexpr int TM_MAX  = N_TOK / TM;   // 64 worst-case token tiles per expert

typedef __attribute__((ext_vector_type(8))) short bf16x8;
typedef __attribute__((ext_vector_type(4))) float f32x4;

__device__ __forceinline__ short f2bf(float f) {
    unsigned u = __float_as_uint(f);
    u += 0x7FFF + ((u >> 16) & 1);   // RNE
    return (short)(u >> 16);
}

__device__ __forceinline__ void gload16(const void* g, void* l) {
    __builtin_amdgcn_global_load_lds(
        (const __attribute__((address_space(1))) unsigned int*)g,
        (__attribute__((address_space(3))) unsigned int*)l, 16, 0, 0);
}

// ---------------------------------------------------------------------------
// fp32 -> bf16 bulk convert (memory-bound, vectorized: 32B in, 16B out / thread)
// ---------------------------------------------------------------------------
__global__ __launch_bounds__(256) void cvt_kernel(
    const float* __restrict__ in, short* __restrict__ out, int n8)
{
    int stride = gridDim.x * 256;
    for (int i = blockIdx.x * 256 + threadIdx.x; i < n8; i += stride) {
        const float4* p = (const float4*)in + (size_t)i * 2;
        float4 a = p[0], b = p[1];
        bf16x8 v;
        v[0] = f2bf(a.x); v[1] = f2bf(a.y); v[2] = f2bf(a.z); v[3] = f2bf(a.w);
        v[4] = f2bf(b.x); v[5] = f2bf(b.y); v[6] = f2bf(b.z); v[7] = f2bf(b.w);
        *(bf16x8*)(out + (size_t)i * 8) = v;
    }
}

// ---------------------------------------------------------------------------
// Kernel 1: gating. One wave per token.
// ---------------------------------------------------------------------------
__global__ __launch_bounds__(256) void gate_kernel(
    const float* __restrict__ x, const float* __restrict__ gate_w,
    const float* __restrict__ gate_b, int* __restrict__ topk_idx,
    float* __restrict__ topk_w, int* __restrict__ counts,
    float* __restrict__ ent_partial)
{
    __shared__ float ent_s[4];
    const int wv = threadIdx.x >> 6;
    const int lane = threadIdx.x & 63;
    const int t = blockIdx.x * 4 + wv;

    float acc[NEXP];
#pragma unroll
    for (int e = 0; e < NEXP; ++e) acc[e] = 0.f;

    const float4* xr = (const float4*)(x + (size_t)t * D_IN);
#pragma unroll
    for (int i = 0; i < D_IN / 256; ++i) {           // 8 iters
        float4 xv = xr[lane + i * 64];
#pragma unroll
        for (int e = 0; e < NEXP; ++e) {
            float4 gv = ((const float4*)(gate_w + e * D_IN))[lane + i * 64];
            acc[e] += xv.x * gv.x + xv.y * gv.y + xv.z * gv.z + xv.w * gv.w;
        }
    }
#pragma unroll
    for (int e = 0; e < NEXP; ++e)
#pragma unroll
        for (int m = 32; m >= 1; m >>= 1) acc[e] += __shfl_xor(acc[e], m, 64);

    if (lane == 0) {
        float lg[NEXP], p[NEXP];
        float mx = -1e30f;
#pragma unroll
        for (int e = 0; e < NEXP; ++e) { lg[e] = acc[e] + gate_b[e]; mx = fmaxf(mx, lg[e]); }
        float s = 0.f;
#pragma unroll
        for (int e = 0; e < NEXP; ++e) { p[e] = expf(lg[e] - mx); s += p[e]; }
        float inv = 1.f / s;
        float ent = 0.f;
#pragma unroll
        for (int e = 0; e < NEXP; ++e) { p[e] *= inv; ent -= p[e] * logf(p[e] + 1e-10f); }
        int e1 = 0; float b1 = p[0];
#pragma unroll
        for (int e = 1; e < NEXP; ++e) if (p[e] > b1) { b1 = p[e]; e1 = e; }
        int e2 = (e1 == 0) ? 1 : 0; float b2 = p[e2];
#pragma unroll
        for (int e = 0; e < NEXP; ++e)
            if (e != e1 && e != ((e1 == 0) ? 1 : 0) && p[e] > b2) { b2 = p[e]; e2 = e; }
        topk_idx[2 * t]     = e1;  topk_idx[2 * t + 1] = e2;
        topk_w[2 * t]       = b1;  topk_w[2 * t + 1]   = b2;
        atomicAdd(&counts[e1], 1);
        atomicAdd(&counts[e2], 1);
        ent_s[wv] = ent;
    }
    __syncthreads();
    if (threadIdx.x == 0)
        ent_partial[blockIdx.x] = ent_s[0] + ent_s[1] + ent_s[2] + ent_s[3];
}

// ---------------------------------------------------------------------------
// Kernel 2: finalize — entropy reduce, loss scalar, expert offsets.
// ---------------------------------------------------------------------------
__global__ __launch_bounds__(256) void finalize_kernel(
    const int* __restrict__ counts, const float* __restrict__ ent_partial,
    int* __restrict__ offsets, float* __restrict__ loss_out)
{
    __shared__ float red[256];
    float s = 0.f;
    for (int i = threadIdx.x; i < N_TOK / 4; i += 256) s += ent_partial[i];
    red[threadIdx.x] = s;
    __syncthreads();
    for (int st = 128; st > 0; st >>= 1) {
        if (threadIdx.x < st) red[threadIdx.x] += red[threadIdx.x + st];
        __syncthreads();
    }
    if (threadIdx.x == 0) {
        float loss = ENT_W * red[0] / (float)N_TOK;
        int off = 0;
        for (int e = 0; e < NEXP; ++e) {
            offsets[e] = off; off += counts[e];
            float r = (float)counts[e] / (float)N_TOK - MAX_USAGE;
            if (r > 0.f) loss += r;
        }
        loss_out[0] = loss;
    }
}

// ---------------------------------------------------------------------------
// Kernel 3: scatter (token, weight) into per-expert lists.
// ---------------------------------------------------------------------------
__global__ __launch_bounds__(256) void scatter_kernel(
    const int* __restrict__ topk_idx, const float* __restrict__ topk_w,
    const int* __restrict__ offsets, int* __restrict__ cursors,
    int* __restrict__ tok_list, float* __restrict__ w_list)
{
    int t = blockIdx.x * 256 + threadIdx.x;
#pragma unroll
    for (int k = 0; k < TOPK; ++k) {
        int e = topk_idx[2 * t + k];
        float w = topk_w[2 * t + k];
        int pos = atomicAdd(&cursors[e], 1);
        int dst = offsets[e] + pos;
        tok_list[dst] = t;
        w_list[dst] = w;
    }
}

// ---------------------------------------------------------------------------
// Kernel 4: grouped GEMM, m97 structure. 128x128 tile, BK=64, 4 waves x 4x4
// 16x16x32 bf16 MFMA. Staging via global_load_lds width=16 (zero VALU).
// LDS linear [128][64]bf16, XOR-swizzle c16^=(row&7) applied on per-lane
// GLOBAL source + on ds_read (rule 21) -> ~2-way conflicts (free).
// Epilogue: atomicAdd weight*(acc+bias), padding rows skipped.
// ---------------------------------------------------------------------------
__global__ __launch_bounds__(256) void moe_gemm(
    const short* __restrict__ xb, const short* __restrict__ wb,
    const float* __restrict__ expert_b, const int* __restrict__ tok_list,
    const float* __restrict__ w_list, const int* __restrict__ counts,
    const int* __restrict__ offsets, float* __restrict__ out)
{
    const int bid = blockIdx.x;
    const int e   = bid / (TM_MAX * TILES_H);
    const int rem = bid % (TM_MAX * TILES_H);
    const int tm  = rem / TILES_H;
    const int th  = rem % TILES_H;

    const int cnt = counts[e];
    if (tm * TM >= cnt) return;
    const int base = offsets[e] + tm * TM;
    const int valid = cnt - tm * TM;

    __shared__ __align__(16) short A_s[TM * BK];   // 16 KB
    __shared__ __align__(16) short B_s[TH * BK];   // 16 KB
    __shared__ int   tok_s[TM];
    __shared__ float wgt_s[TM];

    const int tid = threadIdx.x;
    if (tid < TM) {
        bool v = tid < valid;
        tok_s[tid] = v ? tok_list[base + tid] : 0;
        wgt_s[tid] = v ? w_list[base + tid] : 0.f;
    }
    __syncthreads();

    const int lane = tid & 63;
    const int wv = tid >> 6;

    // staging: wave wv owns 1KB chunks wv*4+j (j=0..3) of each tile.
    // chunk c covers rows 8c..8c+7; lane l -> row c*8+(l>>3), slot l&7.
    // source slot is XOR-swizzled so LDS stays linear.
    const char* asrc[4];
    const char* bsrc[4];
    short* adst[4];
    short* bdst[4];
#pragma unroll
    for (int j = 0; j < 4; ++j) {
        int c = wv * 4 + j;
        int r = c * 8 + (lane >> 3);
        int c16 = (lane & 7) ^ (r & 7);
        asrc[j] = (const char*)(xb + (size_t)tok_s[r] * D_IN) + c16 * 16;
        bsrc[j] = (const char*)(wb + ((size_t)e * H_OUT + th * TH + r) * D_IN) + c16 * 16;
        adst[j] = A_s + c * 512;    // wave-uniform
        bdst[j] = B_s + c * 512;
    }

    const int rr = lane & 15, kg = lane >> 4;
    const int wr = wv >> 1, wc = wv & 1;

    // fragment LDS offsets (short units), swizzled
    int aoff[4][2], boff[4][2];
#pragma unroll
    for (int mi = 0; mi < 4; ++mi)
#pragma unroll
        for (int k2 = 0; k2 < 2; ++k2) {
            int row = wr * 64 + mi * 16 + rr;
            int c16 = (k2 * 4 + kg) ^ (row & 7);
            aoff[mi][k2] = row * 64 + c16 * 8;
            int rowb = wc * 64 + mi * 16 + rr;
            int c16b = (k2 * 4 + kg) ^ (rowb & 7);
            boff[mi][k2] = rowb * 64 + c16b * 8;
        }

    f32x4 acc[4][4] = {};

    for (int kk = 0; kk < D_IN / BK; ++kk) {       // 32 iters
#pragma unroll
        for (int j = 0; j < 4; ++j) {
            gload16(asrc[j], adst[j]); asrc[j] += BK * 2;
            gload16(bsrc[j], bdst[j]); bsrc[j] += BK * 2;
        }
        __syncthreads();   // compiler drains vmcnt before barrier

#pragma unroll
        for (int k2 = 0; k2 < 2; ++k2) {
            bf16x8 af[4], bv[4];
#pragma unroll
            for (int mi = 0; mi < 4; ++mi) af[mi] = *(const bf16x8*)&A_s[aoff[mi][k2]];
#pragma unroll
            for (int ni = 0; ni < 4; ++ni) bv[ni] = *(const bf16x8*)&B_s[boff[ni][k2]];
#pragma unroll
            for (int mi = 0; mi < 4; ++mi)
#pragma unroll
                for (int ni = 0; ni < 4; ++ni)
                    acc[mi][ni] = __builtin_amdgcn_mfma_f32_16x16x32_bf16(
                        af[mi], bv[ni], acc[mi][ni], 0, 0, 0);
        }
        __syncthreads();
    }

    // epilogue: C/D layout col=lane&15, row=(lane>>4)*4+i
    const float* bias = expert_b + (size_t)e * H_OUT + th * TH;
#pragma unroll
    for (int mi = 0; mi < 4; ++mi) {
#pragma unroll
        for (int ni = 0; ni < 4; ++ni) {
            int col = wc * 64 + ni * 16 + rr;
            float be = bias[col];
#pragma unroll
            for (int i = 0; i < 4; ++i) {
                int r = wr * 64 + mi * 16 + kg * 4 + i;
                if (r < valid) {
                    float val = wgt_s[r] * (acc[mi][ni][i] + be);
                    atomicAdd(&out[(size_t)tok_s[r] * H_OUT + th * TH + col], val);
                }
            }
        }
    }
}

// ---------------------------------------------------------------------------
// Workspace layout (requires ws_size >= ~163 MB):
//   0        topk_idx   64 KB
//   64K      topk_w     64 KB
//   128K     counts(32B) cursors(+64) offsets(+128) ent_partial(+256, 8KB)
//   160K     tok_list   64 KB
//   224K     w_list     64 KB
//   1M       xb   bf16  32 MB
//   34M      wb   bf16  128 MB   (ends at 162 MB)
// ---------------------------------------------------------------------------
extern "C" void kernel_launch(void* const* d_in, const int* in_sizes, int n_in,
                              void* d_out, int out_size, void* d_ws, size_t ws_size,
                              hipStream_t stream) {
    const float* x        = (const float*)d_in[0];
    const float* gate_w   = (const float*)d_in[1];
    const float* gate_b   = (const float*)d_in[2];
    const float* expert_w = (const float*)d_in[3];
    const float* expert_b = (const float*)d_in[4];
    float* out = (float*)d_out;
    char* ws = (char*)d_ws;

    int*   topk_idx    = (int*)(ws);
    float* topk_w      = (float*)(ws + (64 << 10));
    int*   counts      = (int*)(ws + (128 << 10));
    int*   cursors     = (int*)(ws + (128 << 10) + 64);
    int*   offsets     = (int*)(ws + (128 << 10) + 128);
    float* ent_partial = (float*)(ws + (128 << 10) + 256);
    int*   tok_list    = (int*)(ws + (160 << 10));
    float* w_list      = (float*)(ws + (224 << 10));
    short* xb          = (short*)(ws + (1ull << 20));
    short* wb          = (short*)(ws + (34ull << 20));

    hipMemsetAsync(counts, 0, 256, stream);                 // counts+cursors
    hipMemsetAsync(d_out, 0, (size_t)out_size * sizeof(float), stream);

    cvt_kernel<<<4096, 256, 0, stream>>>(x, xb, (N_TOK * D_IN) / 8);
    cvt_kernel<<<4096, 256, 0, stream>>>(expert_w, wb, (NEXP * H_OUT * D_IN) / 8);

    gate_kernel<<<N_TOK / 4, 256, 0, stream>>>(x, gate_w, gate_b, topk_idx,
                                               topk_w, counts, ent_partial);
    finalize_kernel<<<1, 256, 0, stream>>>(counts, ent_partial, offsets,
                                           out + (size_t)N_TOK * H_OUT);
    scatter_kernel<<<N_TOK / 256, 256, 0, stream>>>(topk_idx, topk_w, offsets,
                                                    cursors, tok_list, w_list);
    moe_gemm<<<NEXP * TM_MAX * TILES_H, 256, 0, stream>>>(
        xb, wb, expert_b, tok_list, w_list, counts, offsets, out);
}